// Round 7
// baseline (232.345 us; speedup 1.0000x reference)
//
#include <hip/hip_runtime.h>

// NonMaxSuppression: 3x3 local max + thr>=0.6 + 10px border -> ordered (y,x) coords.
// Input fixed: (16,1,1536,1536) fp32.
// Pass1: barrier-free rolling-register NMS. 768 blocks x 192 threads; block = 32 rows,
//        thread = 8 aligned cols (TWO aligned float4/row). One wave-shuffle pair + 2
//        predicated edge scalars give the 10-wide halo; separable v_max3 vertical
//        window rolls in registers. Halo amp 34/32 (was 18/16). u64 masks + counts.
// Pass2 (fused scan+scatter, R3-proven): 768 blocks x 768 threads (32-row strips,
//        now 1:1 with pass1 blocks -> single counts[t] load for the offset reduce).
//        Replay masks into LDS as packed (y|x<<16), then COALESCED write of both
//        output streams. Direct-scatter fallback past CAP keeps any input correct.
#define W 1536
#define H 1536
#define NB 16
#define NROWS (NB * H)          // 24576
#define SH 32                   // rows per strip (pass1 AND pass2, 1:1)
#define NBLK (NROWS / SH)       // 768
#define BLOCK1 192              // 1536/8 cols per thread
#define NW1 (BLOCK1 / 64)       // 3 waves
#define CPR 24                  // u64 chunks per row
#define NMASK (NROWS * CPR)     // 589824 u64 = 4.72 MB
#define BLOCK2 (SH * CPR)       // 768 threads = chunks per strip
#define NW2 (BLOCK2 / 64)       // 12 waves
#define CAP 6144                // staged items/block (24 KB LDS); expected ~5340 (+11 sigma)
#define REP_THR 0.6f

__device__ __forceinline__ float max3f(float a, float b, float c) {
    return fmaxf(fmaxf(a, b), c);  // v_max3_f32
}

struct f8 { float4 a, b; };

__global__ __launch_bounds__(BLOCK1) void nms_pass1(const float* __restrict__ in,
                                                    unsigned long long* __restrict__ masks,
                                                    unsigned int* __restrict__ counts) {
    const int t = threadIdx.x;
    const int lane = t & 63;
    const int wv = t >> 6;
    const int blk = blockIdx.x;
    const int r0 = blk * SH;                 // first output row (global)
    const int ytile = blk % (H / SH);        // strip index within image (48/strip)

    const int c0 = 8 * t;                    // aligned column base (32B-aligned)
    // wave-edge halo columns (clamped; clamped lanes masked by colm)
    const int cl = (t == 0) ? 0 : c0 - 1;
    const int cr = (t == BLOCK1 - 1) ? (W - 1) : c0 + 8;

    // x-border byte mask, valid x in [10, 1526); bit j <-> col 8t+j
    unsigned colm = 0xFFu;
    if (t == 0) colm = 0u;
    else if (t == 1) colm = 0xFCu;           // cols 8,9 invalid
    if (t == BLOCK1 - 1) colm = 0u;
    else if (t == BLOCK1 - 2) colm = 0x3Fu;  // cols 1526,1527 invalid

    auto rowp = [&](int i) {                 // input row rel i (rel 0 = r0-1), clamped
        int ir = r0 - 1 + i;
        ir = ir < 0 ? 0 : (ir >= NROWS ? NROWS - 1 : ir);
        return in + (size_t)ir * W;
    };

    // 8-wide horizontal max-halo: h[j] = max of cols c0+j-1 .. c0+j+1
    auto mkhalo = [&](float4 va, float4 vb, float l, float r) {
        float lw = __shfl_up(vb.w, 1, 64);
        if (lane == 0) lw = l;               // from predicated edge load
        float rx = __shfl_down(va.x, 1, 64);
        if (lane == 63) rx = r;
        f8 h;
        h.a.x = max3f(lw,   va.x, va.y);
        h.a.y = max3f(va.x, va.y, va.z);
        h.a.z = max3f(va.y, va.z, va.w);
        h.a.w = max3f(va.z, va.w, vb.x);
        h.b.x = max3f(va.w, vb.x, vb.y);
        h.b.y = max3f(vb.x, vb.y, vb.z);
        h.b.z = max3f(vb.y, vb.z, vb.w);
        h.b.w = max3f(vb.z, vb.w, rx);
        return h;
    };

    // prologue: rows rel 0,1 and prefetch rel 2
    float4 va0 = *(const float4*)(rowp(0) + c0);
    float4 vb0 = *(const float4*)(rowp(0) + c0 + 4);
    float lw0 = 0.f, rx0 = 0.f;
    if (lane == 0) lw0 = rowp(0)[cl];
    if (lane == 63) rx0 = rowp(0)[cr];
    float4 va1 = *(const float4*)(rowp(1) + c0);
    float4 vb1 = *(const float4*)(rowp(1) + c0 + 4);
    float lw1 = 0.f, rx1 = 0.f;
    if (lane == 0) lw1 = rowp(1)[cl];
    if (lane == 63) rx1 = rowp(1)[cr];
    float4 vaN = *(const float4*)(rowp(2) + c0);
    float4 vbN = *(const float4*)(rowp(2) + c0 + 4);
    float lwN = 0.f, rxN = 0.f;
    if (lane == 0) lwN = rowp(2)[cl];
    if (lane == 63) rxN = rowp(2)[cr];

    f8 hA = mkhalo(va0, vb0, lw0, rx0);
    f8 hB = mkhalo(va1, vb1, lw1, rx1);
    f8 ctr;                                  // center row values (cols c0..c0+7)
    ctr.a = va1; ctr.b = vb1;

    unsigned cnt = 0;
#pragma unroll 8
    for (int i = 2; i <= SH + 1; ++i) {
        float4 va = vaN, vb = vbN;
        float lwc = lwN, rxc = rxN;
        vaN = *(const float4*)(rowp(i + 1) + c0);       // depth-1 prefetch (clamped)
        vbN = *(const float4*)(rowp(i + 1) + c0 + 4);
        lwN = 0.f; rxN = 0.f;
        if (lane == 0) lwN = rowp(i + 1)[cl];
        if (lane == 63) rxN = rowp(i + 1)[cr];

        f8 hC = mkhalo(va, vb, lwc, rxc);

        const int yloc = ytile * SH + (i - 2);          // image-local y of emitted row
        unsigned nib = 0u;
        if (yloc >= 10 && yloc < H - 10) {
            nib |= (ctr.a.x >= fmaxf(max3f(hA.a.x, hB.a.x, hC.a.x), REP_THR)) ?   1u : 0u;
            nib |= (ctr.a.y >= fmaxf(max3f(hA.a.y, hB.a.y, hC.a.y), REP_THR)) ?   2u : 0u;
            nib |= (ctr.a.z >= fmaxf(max3f(hA.a.z, hB.a.z, hC.a.z), REP_THR)) ?   4u : 0u;
            nib |= (ctr.a.w >= fmaxf(max3f(hA.a.w, hB.a.w, hC.a.w), REP_THR)) ?   8u : 0u;
            nib |= (ctr.b.x >= fmaxf(max3f(hA.b.x, hB.b.x, hC.b.x), REP_THR)) ?  16u : 0u;
            nib |= (ctr.b.y >= fmaxf(max3f(hA.b.y, hB.b.y, hC.b.y), REP_THR)) ?  32u : 0u;
            nib |= (ctr.b.z >= fmaxf(max3f(hA.b.z, hB.b.z, hC.b.z), REP_THR)) ?  64u : 0u;
            nib |= (ctr.b.w >= fmaxf(max3f(hA.b.w, hB.b.w, hC.b.w), REP_THR)) ? 128u : 0u;
            nib &= colm;
        }
        cnt += __popc(nib);
        // fold 8 lanes' bytes -> u64 chunk (lane%8==0 stores); byte k of chunk = lane 8c+k
        unsigned x = nib;
        x |= __shfl_down(x, 1, 64) << 8;
        x |= __shfl_down(x, 2, 64) << 16;
        unsigned hi = __shfl_down(x, 4, 64);
        if ((lane & 7) == 0) {
            unsigned long long m64 = (unsigned long long)x | ((unsigned long long)hi << 32);
            masks[(size_t)(r0 + i - 2) * CPR + (t >> 3)] = m64;
        }
        hA = hB; hB = hC; ctr.a = va; ctr.b = vb;
    }

#pragma unroll
    for (int o = 32; o > 0; o >>= 1) cnt += __shfl_down(cnt, o, 64);
    __shared__ unsigned wsum[NW1];
    if (lane == 0) wsum[wv] = cnt;
    __syncthreads();
    if (t == 0) {
        unsigned s = 0;
#pragma unroll
        for (int k = 0; k < NW1; ++k) s += wsum[k];
        counts[blk] = s;
    }
}

// Pass 2: fused scan + scatter with LDS-staged coalesced output (R3-proven shape).
// One u64 chunk per thread (row-major => thread order == spatial order).
// Strips are 1:1 with pass1 blocks: offset = sum of counts[0..blk), 1 load/thread.
__global__ __launch_bounds__(BLOCK2) void nms_scatter(const unsigned long long* __restrict__ masks,
                                                      const unsigned int* __restrict__ counts,
                                                      int* __restrict__ out, unsigned int K) {
    __shared__ unsigned wtot[NW2];
    __shared__ unsigned sred[NW2];
    __shared__ unsigned pk[CAP];             // packed y | x<<16
    const int t = threadIdx.x, lane = t & 63, wv = t >> 6;
    const int blk = blockIdx.x;
    unsigned long long bits = masks[(size_t)blk * BLOCK2 + t];
    const unsigned cnt = (unsigned)__popcll(bits);
    unsigned incl = cnt;
#pragma unroll
    for (int o = 1; o < 64; o <<= 1) {
        unsigned u = __shfl_up(incl, o, 64);
        if (lane >= o) incl += u;
    }
    // exclusive block offset: sum of counts[0..blk) over 768 pass1 counts (1:1 strips)
    unsigned part = (t < blk) ? counts[t] : 0u;
#pragma unroll
    for (int o = 32; o > 0; o >>= 1) part += __shfl_down(part, o, 64);
    if (lane == 63) wtot[wv] = incl;
    if (lane == 0) sred[wv] = part;
    __syncthreads();
    unsigned blockBase = 0, blockCnt = 0, wbase = 0;
#pragma unroll
    for (int k = 0; k < NW2; ++k) {
        blockBase += sred[k];
        blockCnt += wtot[k];
        if (k < wv) wbase += wtot[k];
    }
    unsigned local = wbase + (incl - cnt);   // block-local index of this thread's first item
    if (bits) {
        const int y = (blk % (H / SH)) * SH + t / CPR;   // image-local row
        const int x0 = (t % CPR) * 64;
        while (bits) {
            int j = __builtin_ctzll(bits);
            bits &= bits - 1ull;
            if (local < CAP) {
                pk[local] = (unsigned)y | ((unsigned)(x0 + j) << 16);
            } else {                          // overflow fallback (correct for any input)
                unsigned g = blockBase + local;
                if (g < K) { out[g] = y; out[K + g] = x0 + j; }
            }
            ++local;
        }
    }
    __syncthreads();
    const unsigned lim = blockCnt < CAP ? blockCnt : CAP;
    for (unsigned i = t; i < lim; i += BLOCK2) {
        unsigned g = blockBase + i;
        if (g < K) {
            unsigned p = pk[i];
            out[g] = (int)(p & 0xFFFFu);
            out[K + g] = (int)(p >> 16);
        }
    }
}

extern "C" void kernel_launch(void* const* d_in, const int* in_sizes, int n_in,
                              void* d_out, int out_size, void* d_ws, size_t ws_size,
                              hipStream_t stream) {
    const float* in = (const float*)d_in[0];
    int* out = (int*)d_out;
    unsigned long long* masks = (unsigned long long*)d_ws;
    unsigned int* counts = (unsigned int*)((char*)d_ws + (size_t)NMASK * 8);
    const unsigned K = (unsigned)(out_size / 2);

    nms_pass1<<<NBLK, BLOCK1, 0, stream>>>(in, masks, counts);
    nms_scatter<<<NBLK, BLOCK2, 0, stream>>>(masks, counts, out, K);
}